// Round 1
// baseline (8692.393 us; speedup 1.0000x reference)
//
#include <hip/hip_runtime.h>
#include <hip/hip_bf16.h>
#include <cstdint>

#define TPB 256
#define SCALE 0.17677669529663687f  // 32^-0.5

typedef float f4v __attribute__((ext_vector_type(4)));
typedef short s4v __attribute__((ext_vector_type(4)));

__device__ __forceinline__ float b2f(short s){
  return __uint_as_float(((unsigned)(unsigned short)s) << 16);
}
__device__ __forceinline__ short f2b(float f){
  unsigned u = __float_as_uint(f);
  unsigned r = (u + 0x7fffu + ((u >> 16) & 1u)) >> 16;
  return (short)r;
}
__device__ __forceinline__ float geluf(float x){
  return 0.5f * x * (1.0f + erff(x * 0.7071067811865476f));
}

// ---------------- Kernel A shared memory: 79360 B -> 2 WG/CU ----------------
struct SmemA {
  short xln[4][64][32];   // LN'd window tokens, bf16 bits        (16384 B)
  short pos[64][32];      // sine positional table, bf16          ( 4096 B)
  short wst[128][32];     // weight staging chunk, bf16           ( 8192 B)
  short buf[3][64][132];  // q/k/v tiles, stride 132 (pad)        (50688 B)
};

__device__ __forceinline__ void stageW(const float* __restrict__ W, int ld, int colBase,
                                       int rows, int srcRow, int dstRow,
                                       short (*wst)[32], int t){
  int total = rows * 8;
  for (int fid = t; fid < total; fid += TPB){
    int o = fid >> 3, q4 = fid & 7;
    f4v w = *(const f4v*)(W + (size_t)(srcRow + o) * ld + colBase + q4 * 4);
    s4v s;
    s[0] = f2b(w[0]); s[1] = f2b(w[1]); s[2] = f2b(w[2]); s[3] = f2b(w[3]);
    *(s4v*)&wst[dstRow + o][q4 * 4] = s;
  }
}

// gacc[oi] += sum_k vin[k] * wst[oi*4+g][k]   (k = 0..31)
__device__ __forceinline__ void accumG(float* gacc, const float* vin,
                                       const short (*wst)[32], int g){
  #pragma unroll
  for (int oi = 0; oi < 32; ++oi){
    int o = oi * 4 + g;
    float acc = gacc[oi];
    #pragma unroll
    for (int k4 = 0; k4 < 8; ++k4){
      s4v wv = *(const s4v*)&wst[o][k4 * 4];
      acc += vin[k4*4+0] * b2f(wv[0]);
      acc += vin[k4*4+1] * b2f(wv[1]);
      acc += vin[k4*4+2] * b2f(wv[2]);
      acc += vin[k4*4+3] * b2f(wv[3]);
    }
    gacc[oi] = acc;
  }
}

// dst[nl][dd*4+g] = mul * sum_c xr[c] * wst[dd*4+g][c]
__device__ __forceinline__ void projEA(const float* xr, short (*dst)[132], int nl, int g,
                                       const short (*wst)[32], float mul){
  for (int dd = 0; dd < 32; ++dd){
    int d = dd * 4 + g;
    float acc = 0.f;
    #pragma unroll
    for (int c4 = 0; c4 < 8; ++c4){
      s4v wv = *(const s4v*)&wst[d][c4 * 4];
      acc += xr[c4*4+0] * b2f(wv[0]);
      acc += xr[c4*4+1] * b2f(wv[1]);
      acc += xr[c4*4+2] * b2f(wv[2]);
      acc += xr[c4*4+3] * b2f(wv[3]);
    }
    dst[nl][d] = f2b(acc * mul);
  }
}

// one EA attention unit (head h, D=32) + GEGLU accumulation into g1a/g2a
__device__ __forceinline__ void eaAttn(SmemA& sm, int qb_, int kb_, int vb_, int h,
                                       int cb, int cb2,
                                       float* g1a, float* g2a,
                                       const float* __restrict__ fc11w,
                                       const float* __restrict__ fc12w,
                                       int nl, int g, int t){
  const int hb = h * 32;
  float q32[32];
  #pragma unroll
  for (int d4 = 0; d4 < 8; ++d4){
    s4v qa = *(const s4v*)&sm.buf[qb_][nl][hb + d4*4];
    q32[d4*4+0] = b2f(qa[0]); q32[d4*4+1] = b2f(qa[1]);
    q32[d4*4+2] = b2f(qa[2]); q32[d4*4+3] = b2f(qa[3]);
  }
  float p[16];
  #pragma unroll
  for (int jj = 0; jj < 16; ++jj){
    int j = jj*4 + g;
    float a = 0.f;
    #pragma unroll
    for (int d4 = 0; d4 < 8; ++d4){
      s4v kv = *(const s4v*)&sm.buf[kb_][j][hb + d4*4];
      a += q32[d4*4+0]*b2f(kv[0]) + q32[d4*4+1]*b2f(kv[1])
         + q32[d4*4+2]*b2f(kv[2]) + q32[d4*4+3]*b2f(kv[3]);
    }
    p[jj] = a;
  }
  float mx = p[0];
  #pragma unroll
  for (int jj = 1; jj < 16; ++jj) mx = fmaxf(mx, p[jj]);
  mx = fmaxf(mx, __shfl_xor(mx, 1));
  mx = fmaxf(mx, __shfl_xor(mx, 2));
  float sum = 0.f;
  #pragma unroll
  for (int jj = 0; jj < 16; ++jj){ p[jj] = expf(p[jj] - mx); sum += p[jj]; }
  sum += __shfl_xor(sum, 1);
  sum += __shfl_xor(sum, 2);
  float inv = 1.0f / sum;

  float outp[32];
  #pragma unroll
  for (int k = 0; k < 32; ++k) outp[k] = 0.f;
  #pragma unroll
  for (int jj = 0; jj < 16; ++jj){
    int j = jj*4 + g;
    float pv = p[jj];
    #pragma unroll
    for (int d4 = 0; d4 < 8; ++d4){
      s4v vv = *(const s4v*)&sm.buf[vb_][j][hb + d4*4];
      outp[d4*4+0] += pv * b2f(vv[0]);
      outp[d4*4+1] += pv * b2f(vv[1]);
      outp[d4*4+2] += pv * b2f(vv[2]);
      outp[d4*4+3] += pv * b2f(vv[3]);
    }
  }
  #pragma unroll
  for (int k = 0; k < 32; ++k) outp[k] += __shfl_xor(outp[k], 1);
  #pragma unroll
  for (int k = 0; k < 32; ++k) outp[k] += __shfl_xor(outp[k], 2);
  #pragma unroll
  for (int k = 0; k < 32; ++k) outp[k] *= inv;

  __syncthreads();
  stageW(fc11w, 1536, cb, 128, 0, 0, sm.wst, t);
  __syncthreads();
  accumG(g1a, outp, sm.wst, g);
  __syncthreads();
  stageW(fc12w, 1536, cb, 128, 0, 0, sm.wst, t);
  __syncthreads();
  accumG(g2a, outp, sm.wst, g);
  if (cb2 >= 0){  // e==0 fold: same output feeds ea1 block too
    __syncthreads();
    stageW(fc11w, 1536, cb2, 128, 0, 0, sm.wst, t);
    __syncthreads();
    accumG(g1a, outp, sm.wst, g);
    __syncthreads();
    stageW(fc12w, 1536, cb2, 128, 0, 0, sm.wst, t);
    __syncthreads();
    accumG(g2a, outp, sm.wst, g);
  }
}

__global__ __launch_bounds__(256, 2) void kernelA(
    const float* __restrict__ x,
    const float* __restrict__ ln1g, const float* __restrict__ ln1b,
    const float* __restrict__ wea,  const float* __restrict__ wsa,
    const float* __restrict__ rpb,
    const float* __restrict__ fc11w, const float* __restrict__ fc11b,
    const float* __restrict__ fc12w, const float* __restrict__ fc12b,
    const float* __restrict__ fc2w,  const float* __restrict__ fc2b,
    float* __restrict__ out)
{
  __shared__ SmemA sm;
  const int t  = threadIdx.x;
  const int bw = blockIdx.x;
  const int b  = bw >> 8, hw = bw & 255, hi = hw >> 4, wj = hw & 15;

  // ---------------- Phase 0: window load + LayerNorm + positional table ----
  {
    const int e = t >> 6, n = t & 63;
    const int c = n >> 1, i0 = (n & 1) * 4;
    // x[b, e, c, hi*8 + i, wj*8 + j]; token n channel c' -> (i = i0 + c'/8, j = c'%8)
    const float* src = x + ((size_t)((b*4 + e)*32 + c) * 128 + hi*8) * 128 + wj*8;
    float v[32];
    #pragma unroll
    for (int ii = 0; ii < 4; ++ii){
      f4v a  = *(const f4v*)(src + (size_t)(i0+ii)*128);
      f4v bb = *(const f4v*)(src + (size_t)(i0+ii)*128 + 4);
      v[ii*8+0]=a[0]; v[ii*8+1]=a[1]; v[ii*8+2]=a[2]; v[ii*8+3]=a[3];
      v[ii*8+4]=bb[0]; v[ii*8+5]=bb[1]; v[ii*8+6]=bb[2]; v[ii*8+7]=bb[3];
    }
    float mu = 0.f;
    #pragma unroll
    for (int k = 0; k < 32; ++k) mu += v[k];
    mu *= (1.f/32.f);
    float var = 0.f;
    #pragma unroll
    for (int k = 0; k < 32; ++k){ float d = v[k]-mu; var += d*d; }
    var *= (1.f/32.f);
    float rstd = rsqrtf(var + 1e-5f);
    #pragma unroll
    for (int c4 = 0; c4 < 8; ++c4){
      s4v sv;
      sv[0] = f2b((v[c4*4+0]-mu)*rstd*ln1g[c4*4+0] + ln1b[c4*4+0]);
      sv[1] = f2b((v[c4*4+1]-mu)*rstd*ln1g[c4*4+1] + ln1b[c4*4+1]);
      sv[2] = f2b((v[c4*4+2]-mu)*rstd*ln1g[c4*4+2] + ln1b[c4*4+2]);
      sv[3] = f2b((v[c4*4+3]-mu)*rstd*ln1g[c4*4+3] + ln1b[c4*4+3]);
      *(s4v*)&sm.xln[e][n][c4*4] = sv;
    }
    if (e == 0){
      // dim_t[2m] = 10000^(m/8) = 10^(m/2)
      const float invT[8] = {1.f, 0.316227766f, 0.1f, 0.0316227766f,
                             0.01f, 0.00316227766f, 0.001f, 0.000316227766f};
      const float ANG = 6.28318530717958647692f / 8.000001f;
      float ay = (float)((n >> 3) + 1) * ANG;
      float ax = (float)((n & 7) + 1) * ANG;
      #pragma unroll
      for (int m = 0; m < 8; ++m){
        float s, cc;
        sincosf(ay * invT[m], &s, &cc);
        sm.pos[n][2*m]   = f2b(s);
        sm.pos[n][2*m+1] = f2b(cc);
        sincosf(ax * invT[m], &s, &cc);
        sm.pos[n][16+2*m]   = f2b(s);
        sm.pos[n][17+2*m] = f2b(cc);
      }
    }
  }
  __syncthreads();

  const int nl = t >> 2, g = t & 3;   // row nl, quad-lane g
  float g1a[32], g2a[32];
  #pragma unroll
  for (int oi = 0; oi < 32; ++oi){ g1a[oi] = 0.f; g2a[oi] = 0.f; }

  // ---------------- SA branch (head-dim 128, rel-pos bias); y cols [0,512) --
  for (int h = 0; h < 4; ++h){
    __syncthreads();
    stageW(wsa, 32, 0, 32, 0*128 + h*32,  0, sm.wst, t);
    stageW(wsa, 32, 0, 32, 1*128 + h*32, 32, sm.wst, t);
    stageW(wsa, 32, 0, 32, 2*128 + h*32, 64, sm.wst, t);
    __syncthreads();
    // projection: q/k/v[nl][d], d = dd*4+g, input exposure e = dd>>3, col c = d&31
    for (int e = 0; e < 4; ++e){
      float xr[32];
      #pragma unroll
      for (int c4 = 0; c4 < 8; ++c4){
        s4v xa = *(const s4v*)&sm.xln[e][nl][c4*4];
        xr[c4*4+0] = b2f(xa[0]); xr[c4*4+1] = b2f(xa[1]);
        xr[c4*4+2] = b2f(xa[2]); xr[c4*4+3] = b2f(xa[3]);
      }
      for (int dd8 = 0; dd8 < 8; ++dd8){
        int dd = e*8 + dd8;
        int d  = dd*4 + g;
        int cc = d & 31;
        float aq = 0.f, ak = 0.f, av = 0.f;
        #pragma unroll
        for (int c4 = 0; c4 < 8; ++c4){
          s4v wq = *(const s4v*)&sm.wst[ 0 + cc][c4*4];
          s4v wk = *(const s4v*)&sm.wst[32 + cc][c4*4];
          s4v wv = *(const s4v*)&sm.wst[64 + cc][c4*4];
          float x0 = xr[c4*4+0], x1 = xr[c4*4+1], x2 = xr[c4*4+2], x3 = xr[c4*4+3];
          aq += x0*b2f(wq[0]) + x1*b2f(wq[1]) + x2*b2f(wq[2]) + x3*b2f(wq[3]);
          ak += x0*b2f(wk[0]) + x1*b2f(wk[1]) + x2*b2f(wk[2]) + x3*b2f(wk[3]);
          av += x0*b2f(wv[0]) + x1*b2f(wv[1]) + x2*b2f(wv[2]) + x3*b2f(wv[3]);
        }
        sm.buf[0][nl][d] = f2b(aq * SCALE);
        sm.buf[1][nl][d] = f2b(ak);
        sm.buf[2][nl][d] = f2b(av);
      }
    }
    __syncthreads();
    // scores (j = jj*4+g), D = 128
    float p[16];
    #pragma unroll
    for (int jj = 0; jj < 16; ++jj) p[jj] = 0.f;
    for (int d0 = 0; d0 < 16; ++d0){
      float q8[8];
      {
        s4v qa = *(const s4v*)&sm.buf[0][nl][d0*8];
        s4v qb = *(const s4v*)&sm.buf[0][nl][d0*8+4];
        q8[0]=b2f(qa[0]); q8[1]=b2f(qa[1]); q8[2]=b2f(qa[2]); q8[3]=b2f(qa[3]);
        q8[4]=b2f(qb[0]); q8[5]=b2f(qb[1]); q8[6]=b2f(qb[2]); q8[7]=b2f(qb[3]);
      }
      #pragma unroll
      for (int jj = 0; jj < 16; ++jj){
        int j = jj*4 + g;
        s4v ka = *(const s4v*)&sm.buf[1][j][d0*8];
        s4v kb = *(const s4v*)&sm.buf[1][j][d0*8+4];
        p[jj] += q8[0]*b2f(ka[0]) + q8[1]*b2f(ka[1]) + q8[2]*b2f(ka[2]) + q8[3]*b2f(ka[3])
               + q8[4]*b2f(kb[0]) + q8[5]*b2f(kb[1]) + q8[6]*b2f(kb[2]) + q8[7]*b2f(kb[3]);
      }
    }
    // relative position bias
    const int yn = nl >> 3, xn = nl & 7;
    #pragma unroll
    for (int jj = 0; jj < 16; ++jj){
      int j = jj*4 + g;
      int idx = (yn - (j >> 3) + 7) * 15 + (xn - (j & 7) + 7);
      p[jj] += rpb[idx*4 + h];
    }
    // softmax across quad
    float mx = p[0];
    #pragma unroll
    for (int jj = 1; jj < 16; ++jj) mx = fmaxf(mx, p[jj]);
    mx = fmaxf(mx, __shfl_xor(mx, 1));
    mx = fmaxf(mx, __shfl_xor(mx, 2));
    float sum = 0.f;
    #pragma unroll
    for (int jj = 0; jj < 16; ++jj){ p[jj] = expf(p[jj] - mx); sum += p[jj]; }
    sum += __shfl_xor(sum, 1);
    sum += __shfl_xor(sum, 2);
    float inv = 1.0f / sum;
    // P@V in 4 chunks of 32 cols, each immediately contracted into g1/g2
    for (int dc = 0; dc < 4; ++dc){
      float outp[32];
      #pragma unroll
      for (int k = 0; k < 32; ++k) outp[k] = 0.f;
      #pragma unroll
      for (int jj = 0; jj < 16; ++jj){
        int j = jj*4 + g;
        float pv = p[jj];
        #pragma unroll
        for (int d4 = 0; d4 < 8; ++d4){
          s4v vv = *(const s4v*)&sm.buf[2][j][dc*32 + d4*4];
          outp[d4*4+0] += pv * b2f(vv[0]);
          outp[d4*4+1] += pv * b2f(vv[1]);
          outp[d4*4+2] += pv * b2f(vv[2]);
          outp[d4*4+3] += pv * b2f(vv[3]);
        }
      }
      #pragma unroll
      for (int k = 0; k < 32; ++k) outp[k] += __shfl_xor(outp[k], 1);
      #pragma unroll
      for (int k = 0; k < 32; ++k) outp[k] += __shfl_xor(outp[k], 2);
      #pragma unroll
      for (int k = 0; k < 32; ++k) outp[k] *= inv;
      int cb = h*128 + dc*32;
      __syncthreads();
      stageW(fc11w, 1536, cb, 128, 0, 0, sm.wst, t);
      __syncthreads();
      accumG(g1a, outp, sm.wst, g);
      __syncthreads();
      stageW(fc12w, 1536, cb, 128, 0, 0, sm.wst, t);
      __syncthreads();
      accumG(g2a, outp, sm.wst, g);
    }
  }

  // ---------------- EA2: attn(Qe, K0, V0); y cols [1024,1536). e=0 also feeds ea1.
  {
    float xr[32]; // xp0 = xln[0] + pos
    #pragma unroll
    for (int c4 = 0; c4 < 8; ++c4){
      s4v xa = *(const s4v*)&sm.xln[0][nl][c4*4];
      s4v pa = *(const s4v*)&sm.pos[nl][c4*4];
      xr[c4*4+0] = b2f(xa[0]) + b2f(pa[0]);
      xr[c4*4+1] = b2f(xa[1]) + b2f(pa[1]);
      xr[c4*4+2] = b2f(xa[2]) + b2f(pa[2]);
      xr[c4*4+3] = b2f(xa[3]) + b2f(pa[3]);
    }
    __syncthreads();
    stageW(wea, 32, 0, 128, 128, 0, sm.wst, t);  // p=1 rows -> K
    __syncthreads();
    projEA(xr, sm.buf[0], nl, g, sm.wst, 1.0f);  // K0
    __syncthreads();
    stageW(wea, 32, 0, 128, 256, 0, sm.wst, t);  // p=2 rows -> V
    __syncthreads();
    projEA(xr, sm.buf[1], nl, g, sm.wst, 1.0f);  // V0
  }
  for (int e = 0; e < 4; ++e){
    {
      float xr[32]; // xln[e] + pos
      #pragma unroll
      for (int c4 = 0; c4 < 8; ++c4){
        s4v xa = *(const s4v*)&sm.xln[e][nl][c4*4];
        s4v pa = *(const s4v*)&sm.pos[nl][c4*4];
        xr[c4*4+0] = b2f(xa[0]) + b2f(pa[0]);
        xr[c4*4+1] = b2f(xa[1]) + b2f(pa[1]);
        xr[c4*4+2] = b2f(xa[2]) + b2f(pa[2]);
        xr[c4*4+3] = b2f(xa[3]) + b2f(pa[3]);
      }
      __syncthreads();
      stageW(wea, 32, 0, 128, 0, 0, sm.wst, t);   // p=0 rows -> Q
      __syncthreads();
      projEA(xr, sm.buf[2], nl, g, sm.wst, SCALE); // Qe (scaled)
      __syncthreads();
    }
    for (int h = 0; h < 4; ++h){
      int cb  = 1024 + h*128 + e*32;
      int cb2 = (e == 0) ? (512 + h*128) : -1;
      eaAttn(sm, 2, 0, 1, h, cb, cb2, g1a, g2a, fc11w, fc12w, nl, g, t);
    }
  }

  // ---------------- EA1 (e = 1..3): attn(Q0, Ke, Ve); y cols [512,1024) -----
  {
    float xr0[32];
    #pragma unroll
    for (int c4 = 0; c4 < 8; ++c4){
      s4v xa = *(const s4v*)&sm.xln[0][nl][c4*4];
      s4v pa = *(const s4v*)&sm.pos[nl][c4*4];
      xr0[c4*4+0] = b2f(xa[0]) + b2f(pa[0]);
      xr0[c4*4+1] = b2f(xa[1]) + b2f(pa[1]);
      xr0[c4*4+2] = b2f(xa[2]) + b2f(pa[2]);
      xr0[c4*4+3] = b2f(xa[3]) + b2f(pa[3]);
    }
    __syncthreads();
    stageW(wea, 32, 0, 128, 0, 0, sm.wst, t);
    __syncthreads();
    projEA(xr0, sm.buf[0], nl, g, sm.wst, SCALE);  // Q0
  }
  for (int e = 1; e < 4; ++e){
    {
      float xr[32];
      #pragma unroll
      for (int c4 = 0; c4 < 8; ++c4){
        s4v xa = *(const s4v*)&sm.xln[e][nl][c4*4];
        s4v pa = *(const s4v*)&sm.pos[nl][c4*4];
        xr[c4*4+0] = b2f(xa[0]) + b2f(pa[0]);
        xr[c4*4+1] = b2f(xa[1]) + b2f(pa[1]);
        xr[c4*4+2] = b2f(xa[2]) + b2f(pa[2]);
        xr[c4*4+3] = b2f(xa[3]) + b2f(pa[3]);
      }
      __syncthreads();
      stageW(wea, 32, 0, 128, 128, 0, sm.wst, t);
      __syncthreads();
      projEA(xr, sm.buf[1], nl, g, sm.wst, 1.0f);  // Ke
      __syncthreads();
      stageW(wea, 32, 0, 128, 256, 0, sm.wst, t);
      __syncthreads();
      projEA(xr, sm.buf[2], nl, g, sm.wst, 1.0f);  // Ve
      __syncthreads();
    }
    for (int h = 0; h < 4; ++h){
      int cb = 512 + h*128 + e*32;
      eaAttn(sm, 0, 1, 2, h, cb, -1, g1a, g2a, fc11w, fc12w, nl, g, t);
    }
  }

  // ---------------- epilogue: GEGLU nonlin + fc2 + window-reverse + residual -
  __syncthreads();
  float* al = (float*)&sm.buf[0][0][0];  // [64][129] f32, overlays buf
  #pragma unroll
  for (int oi = 0; oi < 32; ++oi){
    int o = oi*4 + g;
    float h1 = g1a[oi] + fc11b[o];
    float h2 = g2a[oi] + fc12b[o];
    al[nl*129 + o] = geluf(h1) * h2;
  }
  __syncthreads();
  float z[32];
  #pragma unroll
  for (int oi = 0; oi < 32; ++oi) z[oi] = fc2b[oi*4 + g];
  for (int oc = 0; oc < 4; ++oc){
    __syncthreads();
    stageW(fc2w, 128, oc*32, 128, 0, 0, sm.wst, t);
    __syncthreads();
    float av[32];
    #pragma unroll
    for (int k = 0; k < 32; ++k) av[k] = al[nl*129 + oc*32 + k];
    accumG(z, av, sm.wst, g);
  }
  {
    const int r = (nl >> 3) * 16 + hi;   // row = ws1*16 + hi
    const int q = (nl & 7) * 16 + wj;    // col = ws2*16 + wj
    #pragma unroll
    for (int oi = 0; oi < 32; ++oi){
      int oo = oi*4 + g;                 // out channel f*32+c, f = oo>>5
      size_t idx = ((size_t)((b*4 + (oo >> 5))*32 + (oo & 31)) * 128 + r) * 128 + q;
      out[idx] = z[oi] + x[idx];         // x1 = y_rev + x_origin (staged in d_out)
    }
  }
}

// ---------------- Kernel B: per-pixel LN + GEGLU MLP + residual (in place) ---
struct SmemB {
  float x1t[128][132];   // 67584 B
  short xnt[128][132];   // 33792 B
  short at [128][132];   // 33792 B
  short wst[128][32];    //  8192 B
};                       // 143360 B total

__global__ __launch_bounds__(256) void kernelB(
    const float* __restrict__ ln2g, const float* __restrict__ ln2b,
    const float* __restrict__ m11w, const float* __restrict__ m11b,
    const float* __restrict__ m12w, const float* __restrict__ m12b,
    const float* __restrict__ m2w,  const float* __restrict__ m2b,
    float* __restrict__ out)
{
  __shared__ SmemB sm;
  const int t = threadIdx.x;
  const int b = blockIdx.x >> 7, r = blockIdx.x & 127;
  float* base = out + (size_t)b * 2097152 + (size_t)r * 128;  // [ch*16384 + q]

  // load x1 tile (this WG's disjoint region), then safe to overwrite later
  for (int fid = t; fid < 128*32; fid += TPB){
    int ch = fid >> 5, q4 = fid & 31;
    f4v v = *(const f4v*)(base + (size_t)ch * 16384 + q4 * 4);
    *(f4v*)&sm.x1t[ch][q4*4] = v;
  }
  __syncthreads();
  // LayerNorm over 128 features per pixel
  {
    int q = t >> 1, hf = t & 1;
    float s = 0.f;
    for (int i = 0; i < 64; ++i) s += sm.x1t[hf*64 + i][q];
    s += __shfl_xor(s, 1);
    float mu = s * (1.f/128.f);
    float vv = 0.f;
    for (int i = 0; i < 64; ++i){ float d = sm.x1t[hf*64 + i][q] - mu; vv += d*d; }
    vv += __shfl_xor(vv, 1);
    float rstd = rsqrtf(vv * (1.f/128.f) + 1e-5f);
    for (int i = 0; i < 64; ++i){
      int ch = hf*64 + i;
      sm.xnt[ch][q] = f2b((sm.x1t[ch][q] - mu) * rstd * ln2g[ch] + ln2b[ch]);
    }
  }
  __syncthreads();
  const int ql = t & 63, qt = t >> 6;
  for (int qb = 0; qb < 2; ++qb){
    int q = qb*64 + ql;
    float g1[32], g2[32];
    #pragma unroll
    for (int oi = 0; oi < 32; ++oi){ g1[oi] = m11b[oi*4+qt]; g2[oi] = m12b[oi*4+qt]; }
    for (int kc = 0; kc < 4; ++kc){
      __syncthreads();
      stageW(m11w, 128, kc*32, 128, 0, 0, sm.wst, t);
      __syncthreads();
      float xv[32];
      #pragma unroll
      for (int k = 0; k < 32; ++k) xv[k] = b2f(sm.xnt[kc*32 + k][q]);
      accumG(g1, xv, sm.wst, qt);
      __syncthreads();
      stageW(m12w, 128, kc*32, 128, 0, 0, sm.wst, t);
      __syncthreads();
      accumG(g2, xv, sm.wst, qt);
    }
    #pragma unroll
    for (int oi = 0; oi < 32; ++oi){
      int o = oi*4 + qt;
      sm.at[o][q] = f2b(geluf(g1[oi]) * g2[oi]);
    }
    __syncthreads();
    float z[32];
    #pragma unroll
    for (int oi = 0; oi < 32; ++oi) z[oi] = m2b[oi*4 + qt];
    for (int oc = 0; oc < 4; ++oc){
      __syncthreads();
      stageW(m2w, 128, oc*32, 128, 0, 0, sm.wst, t);
      __syncthreads();
      float av[32];
      #pragma unroll
      for (int k = 0; k < 32; ++k) av[k] = b2f(sm.at[oc*32 + k][q]);
      accumG(z, av, sm.wst, qt);
    }
    #pragma unroll
    for (int oi = 0; oi < 32; ++oi){
      int oo = oi*4 + qt;
      base[(size_t)oo * 16384 + q] = sm.x1t[oo][q] + z[oi];  // out = x1 + t
    }
    __syncthreads();
  }
}

extern "C" void kernel_launch(void* const* d_in, const int* in_sizes, int n_in,
                              void* d_out, int out_size, void* d_ws, size_t ws_size,
                              hipStream_t stream) {
  (void)in_sizes; (void)n_in; (void)out_size; (void)d_ws; (void)ws_size;
  const float* x     = (const float*)d_in[0];
  const float* ln1g  = (const float*)d_in[1];
  const float* ln1b  = (const float*)d_in[2];
  const float* wea   = (const float*)d_in[3];
  const float* wsa   = (const float*)d_in[4];
  const float* rpb   = (const float*)d_in[5];
  const float* fc11w = (const float*)d_in[6];
  const float* fc11b = (const float*)d_in[7];
  const float* fc12w = (const float*)d_in[8];
  const float* fc12b = (const float*)d_in[9];
  const float* fc2w  = (const float*)d_in[10];
  const float* fc2b  = (const float*)d_in[11];
  const float* ln2g  = (const float*)d_in[12];
  const float* ln2b  = (const float*)d_in[13];
  const float* m11w  = (const float*)d_in[14];
  const float* m11b  = (const float*)d_in[15];
  const float* m12w  = (const float*)d_in[16];
  const float* m12b  = (const float*)d_in[17];
  const float* m2w   = (const float*)d_in[18];
  const float* m2b   = (const float*)d_in[19];
  float* outp = (float*)d_out;

  kernelA<<<512, TPB, 0, stream>>>(x, ln1g, ln1b, wea, wsa, rpb,
                                   fc11w, fc11b, fc12w, fc12b, fc2w, fc2b, outp);
  kernelB<<<256, TPB, 0, stream>>>(ln2g, ln2b, m11w, m11b, m12w, m12b, m2w, m2b, outp);
}

// Round 2
// 292.336 us; speedup vs baseline: 29.7343x; 29.7343x over previous
//
#include <hip/hip_runtime.h>
#include <hip/hip_bf16.h>
#include <cstdint>

#define TPB 256
#define SCALE 0.17677669529663687f  // 32^-0.5

typedef float f4v __attribute__((ext_vector_type(4)));
typedef short s4v __attribute__((ext_vector_type(4)));
typedef short short8 __attribute__((ext_vector_type(8)));

__device__ __forceinline__ float b2f(short s){
  return __uint_as_float(((unsigned)(unsigned short)s) << 16);
}
__device__ __forceinline__ short f2b(float f){
  unsigned u = __float_as_uint(f);
  unsigned r = (u + 0x7fffu + ((u >> 16) & 1u)) >> 16;
  return (short)r;
}
__device__ __forceinline__ float geluf(float x){
  return 0.5f * x * (1.0f + erff(x * 0.7071067811865476f));
}

__device__ __forceinline__ f4v MFMA(short8 a, short8 b, f4v c){
  return __builtin_amdgcn_mfma_f32_16x16x32_bf16(a, b, c, 0, 0, 0);
}

// A-pattern fragment from LDS row-major [*][ld]: row = rowBase + (l&15), k = kBase + 8*(l>>4)
__device__ __forceinline__ short8 ldsA(const short* base, int ld, int rowBase, int kBase, int l){
  return *(const short8*)(base + (rowBase + (l & 15)) * ld + kBase + ((l >> 4) << 3));
}

// ws short-offsets
#define WEA_S   0
#define WSA_S   12288
#define FC11_S  24576
#define FC12_S  221184
#define FC2_S   417792
#define M11_S   434176
#define M12_S   450560
#define M2_S    466944
#define POS_S   483328
#define BIAS_B  970752      // bytes (float region)
#define YW_B    1048576     // bytes (bf16 y_win region)

// ---------------------------------------------------------------- prep ----
__global__ void prep(const float* __restrict__ wea, const float* __restrict__ wsa,
                     const float* __restrict__ fc11, const float* __restrict__ fc12,
                     const float* __restrict__ fc2,  const float* __restrict__ m11,
                     const float* __restrict__ m12,  const float* __restrict__ m2,
                     const float* __restrict__ rpb,
                     short* __restrict__ wsS, float* __restrict__ biasT)
{
  int gid = blockIdx.x * TPB + threadIdx.x;
  int stride = gridDim.x * TPB;
  for (int i = gid; i < 483328; i += stride){
    const float* src; int off;
    if      (i < 12288)  { src = wea;  off = i; }
    else if (i < 24576)  { src = wsa;  off = i - 12288; }
    else if (i < 221184) { src = fc11; off = i - 24576; }
    else if (i < 417792) { src = fc12; off = i - 221184; }
    else if (i < 434176) { src = fc2;  off = i - 417792; }
    else if (i < 450560) { src = m11;  off = i - 434176; }
    else if (i < 466944) { src = m12;  off = i - 450560; }
    else                 { src = m2;   off = i - 466944; }
    wsS[i] = f2b(src[off]);
  }
  if (gid < 16384){
    int h = gid >> 12, ij = gid & 4095, i = ij >> 6, j = ij & 63;
    int idx = ((i >> 3) - (j >> 3) + 7) * 15 + ((i & 7) - (j & 7) + 7);
    biasT[gid] = rpb[idx * 4 + h];
  }
  if (gid < 64){
    const float invT[8] = {1.f, 0.316227766f, 0.1f, 0.0316227766f,
                           0.01f, 0.00316227766f, 0.001f, 0.000316227766f};
    const float ANG = 6.28318530717958647692f / 8.000001f;
    float ay = (float)((gid >> 3) + 1) * ANG;
    float ax = (float)((gid & 7) + 1) * ANG;
    #pragma unroll
    for (int m = 0; m < 8; ++m){
      float s, cc;
      sincosf(ay * invT[m], &s, &cc);
      wsS[POS_S + gid*32 + 2*m]      = f2b(s);
      wsS[POS_S + gid*32 + 2*m + 1]  = f2b(cc);
      sincosf(ax * invT[m], &s, &cc);
      wsS[POS_S + gid*32 + 16 + 2*m] = f2b(s);
      wsS[POS_S + gid*32 + 17 + 2*m] = f2b(cc);
    }
  }
}

// -------------------------------------------------------------- kernel A --
struct SmemA {
  short xw[4][64][40];    // 20480 : LN'd tokens (later +pos in place)
  short qp[64][40];       //  5120 : Q tile (wave-private rows)
  short kp[2][64][40];    // 10240 : K tiles, double-buffered
  short vtp[2][32][72];   //  9216 : V^T tiles, double-buffered
  short p[64][72];        //  9216 : softmax P (wave-private rows)
  short ych[64][40];      //  5120 : y chunk (wave-private rows)
  short abuf[64][136];    // 17408 : GEGLU activations
};                        // 76800 B -> 2 WG/CU

// project [64x32] = xw_e @ W[wRow..wRow+32)^T -> dst rows (wave rowtile)
__device__ __forceinline__ void projQK(const short* xsrc, const short* Wg, int wRow,
                                       short* dst, float scl, int w, int l){
  short8 a = ldsA(xsrc, 40, w*16, 0, l);
  int row0 = w*16 + ((l >> 4) << 2);
  #pragma unroll
  for (int ct = 0; ct < 2; ++ct){
    short8 b = *(const short8*)(Wg + (wRow + ct*16 + (l & 15)) * 32 + ((l >> 4) << 3));
    f4v acc = {0.f, 0.f, 0.f, 0.f};
    acc = MFMA(a, b, acc);
    int col = ct*16 + (l & 15);
    #pragma unroll
    for (int r = 0; r < 4; ++r) dst[(row0 + r)*40 + col] = f2b(acc[r] * scl);
  }
}

// same but store transposed: dstVT[feat][tok]
__device__ __forceinline__ void projVT(const short* xsrc, const short* Wg, int wRow,
                                       short* dstVT, int w, int l){
  short8 a = ldsA(xsrc, 40, w*16, 0, l);
  int tok0 = w*16 + ((l >> 4) << 2);
  #pragma unroll
  for (int ct = 0; ct < 2; ++ct){
    short8 b = *(const short8*)(Wg + (wRow + ct*16 + (l & 15)) * 32 + ((l >> 4) << 3));
    f4v acc = {0.f, 0.f, 0.f, 0.f};
    acc = MFMA(a, b, acc);
    int feat = ct*16 + (l & 15);
    s4v pk;
    pk[0] = f2b(acc[0]); pk[1] = f2b(acc[1]); pk[2] = f2b(acc[2]); pk[3] = f2b(acc[3]);
    *(s4v*)(dstVT + feat*72 + tok0) = pk;
  }
}

// s[ct] += Q(rowtile w) . K(rows ct*16..)^T  (K=32)
__device__ __forceinline__ void sStep(const short* Q, const short* K, f4v* s, int w, int l){
  short8 a = ldsA(Q, 40, w*16, 0, l);
  #pragma unroll
  for (int ct = 0; ct < 4; ++ct){
    short8 b = ldsA(K, 40, ct*16, 0, l);
    s[ct] = MFMA(a, b, s[ct]);
  }
}

__device__ __forceinline__ void softmaxP(f4v* s, const float* biasBase,
                                         short* P, int w, int l){
  int row0 = w*16 + ((l >> 4) << 2);
  if (biasBase){
    #pragma unroll
    for (int ct = 0; ct < 4; ++ct)
      #pragma unroll
      for (int r = 0; r < 4; ++r)
        s[ct][r] += biasBase[(row0 + r)*64 + ct*16 + (l & 15)];
  }
  #pragma unroll
  for (int r = 0; r < 4; ++r){
    float m = fmaxf(fmaxf(s[0][r], s[1][r]), fmaxf(s[2][r], s[3][r]));
    m = fmaxf(m, __shfl_xor(m, 1));
    m = fmaxf(m, __shfl_xor(m, 2));
    m = fmaxf(m, __shfl_xor(m, 4));
    m = fmaxf(m, __shfl_xor(m, 8));
    float e0 = expf(s[0][r] - m), e1 = expf(s[1][r] - m);
    float e2 = expf(s[2][r] - m), e3 = expf(s[3][r] - m);
    float sum = e0 + e1 + e2 + e3;
    sum += __shfl_xor(sum, 1);
    sum += __shfl_xor(sum, 2);
    sum += __shfl_xor(sum, 4);
    sum += __shfl_xor(sum, 8);
    float inv = 1.0f / sum;
    int rr = (row0 + r)*72 + (l & 15);
    P[rr +  0] = f2b(e0 * inv);
    P[rr + 16] = f2b(e1 * inv);
    P[rr + 32] = f2b(e2 * inv);
    P[rr + 48] = f2b(e3 * inv);
  }
}

// ych(rowtile w) = P(rowtile w) @ V  (V from VT[32][72])
__device__ __forceinline__ void pvYch(const short* P, const short* VT,
                                      short* ych, int w, int l){
  f4v pv[2] = {{0.f,0.f,0.f,0.f},{0.f,0.f,0.f,0.f}};
  #pragma unroll
  for (int ks = 0; ks < 2; ++ks){
    short8 a = ldsA(P, 72, w*16, ks*32, l);
    #pragma unroll
    for (int ct = 0; ct < 2; ++ct){
      short8 b = *(const short8*)(VT + (ct*16 + (l & 15))*72 + ks*32 + ((l >> 4) << 3));
      pv[ct] = MFMA(a, b, pv[ct]);
    }
  }
  int row0 = w*16 + ((l >> 4) << 2);
  #pragma unroll
  for (int ct = 0; ct < 2; ++ct){
    int col = ct*16 + (l & 15);
    #pragma unroll
    for (int r = 0; r < 4; ++r)
      ych[(row0 + r)*40 + col] = f2b(pv[ct][r]);
  }
}

// g1/g2 (rowtile w, 8 col-tiles) += ych @ fc11/fc12 cols [cb, cb+32) of k-dim
__device__ __forceinline__ void geglu(const short* ych,
                                      const short* fc11, const short* fc12, int cb,
                                      f4v* g1, f4v* g2, int w, int l){
  short8 a = ldsA(ych, 40, w*16, 0, l);
  #pragma unroll
  for (int ct = 0; ct < 8; ++ct){
    short8 b1 = *(const short8*)(fc11 + (ct*16 + (l & 15))*1536 + cb + ((l >> 4) << 3));
    g1[ct] = MFMA(a, b1, g1[ct]);
  }
  #pragma unroll
  for (int ct = 0; ct < 8; ++ct){
    short8 b2 = *(const short8*)(fc12 + (ct*16 + (l & 15))*1536 + cb + ((l >> 4) << 3));
    g2[ct] = MFMA(a, b2, g2[ct]);
  }
}

__global__ __launch_bounds__(256, 2) void kernelA(
    const float* __restrict__ x,
    const float* __restrict__ ln1g, const float* __restrict__ ln1b,
    const float* __restrict__ fc11b_, const float* __restrict__ fc12b_,
    const float* __restrict__ fc2b_,
    const short* __restrict__ wsS, const float* __restrict__ biasT,
    short* __restrict__ yw)
{
  __shared__ SmemA sm;
  const int t = threadIdx.x, l = t & 63, w = t >> 6;
  const int bw = blockIdx.x, b = bw >> 8, hw = bw & 255, hi = hw >> 4, wj = hw & 15;
  const short* wea  = wsS + WEA_S;
  const short* wsa  = wsS + WSA_S;
  const short* fc11 = wsS + FC11_S;
  const short* fc12 = wsS + FC12_S;
  const short* fc2  = wsS + FC2_S;
  const short* posb = wsS + POS_S;

  // ---- phase 0: window load + LayerNorm (token mapping verified in round 1)
  {
    const int e = w, n = l;
    const int c = n >> 1, i0 = (n & 1) * 4;
    const float* src = x + ((size_t)((b*4 + e)*32 + c) * 128 + hi*8) * 128 + wj*8;
    float v[32];
    #pragma unroll
    for (int ii = 0; ii < 4; ++ii){
      f4v a  = *(const f4v*)(src + (size_t)(i0 + ii)*128);
      f4v bb = *(const f4v*)(src + (size_t)(i0 + ii)*128 + 4);
      v[ii*8+0]=a[0]; v[ii*8+1]=a[1]; v[ii*8+2]=a[2]; v[ii*8+3]=a[3];
      v[ii*8+4]=bb[0]; v[ii*8+5]=bb[1]; v[ii*8+6]=bb[2]; v[ii*8+7]=bb[3];
    }
    float mu = 0.f;
    #pragma unroll
    for (int k = 0; k < 32; ++k) mu += v[k];
    mu *= (1.f/32.f);
    float var = 0.f;
    #pragma unroll
    for (int k = 0; k < 32; ++k){ float d = v[k]-mu; var += d*d; }
    var *= (1.f/32.f);
    float rstd = rsqrtf(var + 1e-5f);
    #pragma unroll
    for (int c4 = 0; c4 < 8; ++c4){
      s4v sv;
      sv[0] = f2b((v[c4*4+0]-mu)*rstd*ln1g[c4*4+0] + ln1b[c4*4+0]);
      sv[1] = f2b((v[c4*4+1]-mu)*rstd*ln1g[c4*4+1] + ln1b[c4*4+1]);
      sv[2] = f2b((v[c4*4+2]-mu)*rstd*ln1g[c4*4+2] + ln1b[c4*4+2]);
      sv[3] = f2b((v[c4*4+3]-mu)*rstd*ln1g[c4*4+3] + ln1b[c4*4+3]);
      *(s4v*)&sm.xw[e][n][c4*4] = sv;
    }
  }
  __syncthreads();

  f4v g1[8], g2[8];
  #pragma unroll
  for (int i = 0; i < 8; ++i){
    g1[i] = (f4v){0.f,0.f,0.f,0.f};
    g2[i] = (f4v){0.f,0.f,0.f,0.f};
  }

  // ---- SA branch: y cols [0,512)
  for (int h = 0; h < 4; ++h){
    f4v s[4];
    #pragma unroll
    for (int i = 0; i < 4; ++i) s[i] = (f4v){0.f,0.f,0.f,0.f};
    for (int e = 0; e < 4; ++e){
      projQK(&sm.xw[e][0][0], wsa, h*32,        &sm.qp[0][0],      SCALE, w, l);
      projQK(&sm.xw[e][0][0], wsa, 128 + h*32,  &sm.kp[e&1][0][0], 1.0f,  w, l);
      __syncthreads();
      sStep(&sm.qp[0][0], &sm.kp[e&1][0][0], s, w, l);
    }
    softmaxP(s, biasT + h*4096, &sm.p[0][0], w, l);
    for (int dc = 0; dc < 4; ++dc){
      projVT(&sm.xw[dc][0][0], wsa, 256 + h*32, &sm.vtp[dc&1][0][0], w, l);
      __syncthreads();
      pvYch(&sm.p[0][0], &sm.vtp[dc&1][0][0], &sm.ych[0][0], w, l);
      geglu(&sm.ych[0][0], fc11, fc12, h*128 + dc*32, g1, g2, w, l);
    }
  }

  // ---- convert xw -> xw + pos (in place, for EA branches)
  __syncthreads();
  {
    const int e = w, n = l;
    #pragma unroll
    for (int c4 = 0; c4 < 8; ++c4){
      s4v xa = *(const s4v*)&sm.xw[e][n][c4*4];
      s4v pa = *(const s4v*)(posb + n*32 + c4*4);
      s4v o;
      #pragma unroll
      for (int j = 0; j < 4; ++j) o[j] = f2b(b2f(xa[j]) + b2f(pa[j]));
      *(s4v*)&sm.xw[e][n][c4*4] = o;
    }
  }
  __syncthreads();

  // ---- EA2: attn(Qe, K0, V0); y cols [1024,1536); e==0 also feeds ea1 cols 512+h*128
  for (int h = 0; h < 4; ++h){
    projQK(&sm.xw[0][0][0], wea, 128 + h*32, &sm.kp[h&1][0][0], 1.0f, w, l);
    projVT(&sm.xw[0][0][0], wea, 256 + h*32, &sm.vtp[h&1][0][0], w, l);
    __syncthreads();
    for (int e = 0; e < 4; ++e){
      projQK(&sm.xw[e][0][0], wea, h*32, &sm.qp[0][0], SCALE, w, l);
      f4v s[4];
      #pragma unroll
      for (int i = 0; i < 4; ++i) s[i] = (f4v){0.f,0.f,0.f,0.f};
      sStep(&sm.qp[0][0], &sm.kp[h&1][0][0], s, w, l);
      softmaxP(s, nullptr, &sm.p[0][0], w, l);
      pvYch(&sm.p[0][0], &sm.vtp[h&1][0][0], &sm.ych[0][0], w, l);
      geglu(&sm.ych[0][0], fc11, fc12, 1024 + h*128 + e*32, g1, g2, w, l);
      if (e == 0) geglu(&sm.ych[0][0], fc11, fc12, 512 + h*128, g1, g2, w, l);
    }
  }

  // ---- EA1 (e=1..3): attn(Q0, Ke, Ve); y cols [512,1024)
  {
    int pc = 0;
    for (int h = 0; h < 4; ++h){
      projQK(&sm.xw[0][0][0], wea, h*32, &sm.qp[0][0], SCALE, w, l);
      for (int e = 1; e < 4; ++e){
        int par = pc & 1; ++pc;
        projQK(&sm.xw[e][0][0], wea, 128 + h*32, &sm.kp[par][0][0], 1.0f, w, l);
        projVT(&sm.xw[e][0][0], wea, 256 + h*32, &sm.vtp[par][0][0], w, l);
        __syncthreads();
        f4v s[4];
        #pragma unroll
        for (int i = 0; i < 4; ++i) s[i] = (f4v){0.f,0.f,0.f,0.f};
        sStep(&sm.qp[0][0], &sm.kp[par][0][0], s, w, l);
        softmaxP(s, nullptr, &sm.p[0][0], w, l);
        pvYch(&sm.p[0][0], &sm.vtp[par][0][0], &sm.ych[0][0], w, l);
        geglu(&sm.ych[0][0], fc11, fc12, 512 + h*128 + e*32, g1, g2, w, l);
      }
    }
  }

  // ---- epilogue: bias + GEGLU nonlinearity -> abuf; fc2; store y_win (coalesced)
  {
    int row0 = w*16 + ((l >> 4) << 2);
    #pragma unroll
    for (int ct = 0; ct < 8; ++ct){
      int o = ct*16 + (l & 15);
      float b1 = fc11b_[o], b2 = fc12b_[o];
      #pragma unroll
      for (int r = 0; r < 4; ++r){
        float h1 = g1[ct][r] + b1;
        float h2 = g2[ct][r] + b2;
        sm.abuf[row0 + r][o] = f2b(geluf(h1) * h2);
      }
    }
    f4v z[8];
    #pragma unroll
    for (int i = 0; i < 8; ++i) z[i] = (f4v){0.f,0.f,0.f,0.f};
    #pragma unroll
    for (int ks = 0; ks < 4; ++ks){
      short8 a = ldsA(&sm.abuf[0][0], 136, w*16, ks*32, l);
      #pragma unroll
      for (int ct = 0; ct < 8; ++ct){
        short8 bb = *(const short8*)(fc2 + (ct*16 + (l & 15))*128 + ks*32 + ((l >> 4) << 3));
        z[ct] = MFMA(a, bb, z[ct]);
      }
    }
    short* ywb = yw + (size_t)bw * 8192;
    #pragma unroll
    for (int ct = 0; ct < 8; ++ct){
      int o = ct*16 + (l & 15);
      float bz = fc2b_[o];
      #pragma unroll
      for (int r = 0; r < 4; ++r){
        int n = row0 + r;
        ywb[n*128 + o] = f2b(z[ct][r] + bz);
      }
    }
  }
}

// -------------------------------------------------------------- kernel B --
struct SmemB {
  float x1t[128][132];   // 67584 : x1 = x + y  (native [ch][px])
  short xnt[128][136];   // 34816 : LN'd, px-major [px][ch]
  short ab[64][136];     // 17408 : GEGLU activations (per pass)
};                       // 119808 B

__global__ __launch_bounds__(256) void kernelB(
    const float* __restrict__ x,
    const float* __restrict__ ln2g, const float* __restrict__ ln2b,
    const float* __restrict__ m11b, const float* __restrict__ m12b,
    const float* __restrict__ m2b,
    const short* __restrict__ wsS, const short* __restrict__ yw,
    float* __restrict__ out)
{
  __shared__ SmemB sm;
  const int t = threadIdx.x, l = t & 63, w = t >> 6;
  const int b = blockIdx.x >> 7, rr = blockIdx.x & 127;
  const short* m11 = wsS + M11_S;
  const short* m12 = wsS + M12_S;
  const short* m2  = wsS + M2_S;
  const float* xb = x + (size_t)b * 128 * 16384 + (size_t)rr * 128;

  // 1) load x rows (coalesced)
  for (int fid = t; fid < 4096; fid += TPB){
    int ch = fid >> 5, q4 = fid & 31;
    *(f4v*)&sm.x1t[ch][q4*4] = *(const f4v*)(xb + (size_t)ch * 16384 + q4*4);
  }
  __syncthreads();
  // 2) x1 = x + y (window-layout gather; contiguous 64-ch runs)
  {
    int q = t >> 1, hf = t & 1;
    const short* ys = yw + ((size_t)(b*256 + (rr & 15)*16 + (q & 15)) * 64
                            + (rr >> 4)*8 + (q >> 4)) * 128 + hf*64;
    #pragma unroll
    for (int k = 0; k < 64; ++k)
      sm.x1t[hf*64 + k][q] += b2f(ys[k]);
  }
  __syncthreads();
  // 3) LayerNorm over 128 features per pixel -> xnt[px][ch]
  {
    int q = t >> 1, hf = t & 1;
    float s = 0.f;
    for (int i = 0; i < 64; ++i) s += sm.x1t[hf*64 + i][q];
    s += __shfl_xor(s, 1);
    float mu = s * (1.f/128.f);
    float vv = 0.f;
    for (int i = 0; i < 64; ++i){ float d = sm.x1t[hf*64 + i][q] - mu; vv += d*d; }
    vv += __shfl_xor(vv, 1);
    float rstd = rsqrtf(vv * (1.f/128.f) + 1e-5f);
    for (int i4 = 0; i4 < 16; ++i4){
      s4v o;
      #pragma unroll
      for (int j = 0; j < 4; ++j){
        int ch = hf*64 + i4*4 + j;
        o[j] = f2b((sm.x1t[ch][q] - mu) * rstd * ln2g[ch] + ln2b[ch]);
      }
      *(s4v*)&sm.xnt[q][hf*64 + i4*4] = o;
    }
  }
  __syncthreads();
  // 4) GEGLU MLP via MFMA, two passes of 64 px
  for (int qb = 0; qb < 2; ++qb){
    int px0 = qb*64 + w*16;
    f4v G1[8], G2[8];
    #pragma unroll
    for (int i = 0; i < 8; ++i){
      G1[i] = (f4v){0.f,0.f,0.f,0.f};
      G2[i] = (f4v){0.f,0.f,0.f,0.f};
    }
    #pragma unroll
    for (int ks = 0; ks < 4; ++ks){
      short8 a = ldsA(&sm.xnt[0][0], 136, px0, ks*32, l);
      #pragma unroll
      for (int ct = 0; ct < 8; ++ct){
        short8 b1 = *(const short8*)(m11 + (ct*16 + (l & 15))*128 + ks*32 + ((l >> 4) << 3));
        G1[ct] = MFMA(a, b1, G1[ct]);
      }
      #pragma unroll
      for (int ct = 0; ct < 8; ++ct){
        short8 b2 = *(const short8*)(m12 + (ct*16 + (l & 15))*128 + ks*32 + ((l >> 4) << 3));
        G2[ct] = MFMA(a, b2, G2[ct]);
      }
    }
    int r0 = w*16 + ((l >> 4) << 2);   // local row within the 64-px pass
    #pragma unroll
    for (int ct = 0; ct < 8; ++ct){
      int o = ct*16 + (l & 15);
      float bb1 = m11b[o], bb2 = m12b[o];
      #pragma unroll
      for (int r = 0; r < 4; ++r)
        sm.ab[r0 + r][o] = f2b(geluf(G1[ct][r] + bb1) * (G2[ct][r] + bb2));
    }
    f4v Z[8];
    #pragma unroll
    for (int i = 0; i < 8; ++i) Z[i] = (f4v){0.f,0.f,0.f,0.f};
    #pragma unroll
    for (int ks = 0; ks < 4; ++ks){
      short8 a = ldsA(&sm.ab[0][0], 136, w*16, ks*32, l);
      #pragma unroll
      for (int ct = 0; ct < 8; ++ct){
        short8 bb = *(const short8*)(m2 + (ct*16 + (l & 15))*128 + ks*32 + ((l >> 4) << 3));
        Z[ct] = MFMA(a, bb, Z[ct]);
      }
    }
    #pragma unroll
    for (int ct = 0; ct < 8; ++ct){
      int ch = ct*16 + (l & 15);
      float bz = m2b[ch];
      #pragma unroll
      for (int r = 0; r < 4; ++r){
        int px = px0 + ((l >> 4) << 2) + r;
        sm.x1t[ch][px] += Z[ct][r] + bz;
      }
    }
  }
  __syncthreads();
  // 5) coalesced store
  {
    int ch = t >> 1, qh = t & 1;
    float* ob = out + ((size_t)b*128 + ch) * 16384 + (size_t)rr * 128 + qh*64;
    #pragma unroll
    for (int q4 = 0; q4 < 16; ++q4)
      *(f4v*)(ob + q4*4) = *(const f4v*)&sm.x1t[ch][qh*64 + q4*4];
  }
}

extern "C" void kernel_launch(void* const* d_in, const int* in_sizes, int n_in,
                              void* d_out, int out_size, void* d_ws, size_t ws_size,
                              hipStream_t stream) {
  (void)in_sizes; (void)n_in; (void)out_size; (void)ws_size;
  const float* x     = (const float*)d_in[0];
  const float* ln1g  = (const float*)d_in[1];
  const float* ln1b  = (const float*)d_in[2];
  const float* wea   = (const float*)d_in[3];
  const float* wsa   = (const float*)d_in[4];
  const float* rpb   = (const float*)d_in[5];
  const float* fc11w = (const float*)d_in[6];
  const float* fc11b = (const float*)d_in[7];
  const float* fc12w = (const float*)d_in[8];
  const float* fc12b = (const float*)d_in[9];
  const float* fc2w  = (const float*)d_in[10];
  const float* fc2b  = (const float*)d_in[11];
  const float* ln2g  = (const float*)d_in[12];
  const float* ln2b  = (const float*)d_in[13];
  const float* m11w  = (const float*)d_in[14];
  const float* m11b  = (const float*)d_in[15];
  const float* m12w  = (const float*)d_in[16];
  const float* m12b  = (const float*)d_in[17];
  const float* m2w   = (const float*)d_in[18];
  const float* m2b   = (const float*)d_in[19];

  short* wsS   = (short*)d_ws;
  float* biasT = (float*)((char*)d_ws + BIAS_B);
  short* yw    = (short*)((char*)d_ws + YW_B);

  prep<<<1024, TPB, 0, stream>>>(wea, wsa, fc11w, fc12w, fc2w, m11w, m12w, m2w,
                                 rpb, wsS, biasT);
  kernelA<<<512, TPB, 0, stream>>>(x, ln1g, ln1b, fc11b, fc12b, fc2b,
                                   wsS, biasT, yw);
  kernelB<<<256, TPB, 0, stream>>>(x, ln2g, ln2b, m11b, m12b, m2b,
                                   wsS, yw, (float*)d_out);
}